// Round 8
// baseline (465.749 us; speedup 1.0000x reference)
//
#include <hip/hip_runtime.h>
#include <hip/hip_bf16.h>

// ContrastiveLoss: z (8192x1024 fp32) -> scalar
//   zn = z / max(||z||,eps); S = zn@zn^T; diag=MASK; /T; nll = -S[i,i^4096] + lse(S[i,:]); mean
// R8: (1) k_tile single-buffered 64KB LDS -> 2 blocks/CU so a co-resident block
// hides the barrier-drain + bunched frag-read phase; (2) barrier-free
// k_normalize (one wave per row). fp8 e4m3 16x16x32 MFMA with K-permuted b128
// fragment reads (chunks kg, kg+4), 128B rows + chunk^(row&7) swizzle — all
// R4/R7-verified 0-conflict. Lower-triangle 256x256 tiles, fixed-shift
// logsumexp partials via atomicAdd.

#define N 8192
#define D 1024
#define INV_T 14.285714285714286f
#define NTILES 528
#define ACC_SCALE (INV_T / 1024.0f)  // undo fp8 x32 scaling on both operands

typedef float f32x4 __attribute__((ext_vector_type(4)));
typedef long lx2 __attribute__((ext_vector_type(2)));

__device__ inline void gload16(const void* g, void* l) {
  __builtin_amdgcn_global_load_lds(
      (const __attribute__((address_space(1))) void*)g,
      (__attribute__((address_space(3))) void*)l, 16, 0, 0);
}

// Phase 1: one wave per row, no barriers. Row-normalize, scale x32, fp8 e4m3.
__global__ __launch_bounds__(256) void k_normalize(const float* __restrict__ z,
                                                   unsigned char* __restrict__ zn8,
                                                   float* __restrict__ rowsum) {
  const int t = threadIdx.x;
  const int l = t & 63, w = t >> 6;
  const int row = blockIdx.x * 4 + w;
  if (blockIdx.x < 32) rowsum[blockIdx.x * 256 + t] = 0.0f;
  const float4* zr = (const float4*)(z + (size_t)row * D);
  float4 v[4];
  float ss = 0.f;
#pragma unroll
  for (int j = 0; j < 4; ++j) {
    v[j] = zr[l + 64 * j];
    ss += v[j].x * v[j].x + v[j].y * v[j].y + v[j].z * v[j].z + v[j].w * v[j].w;
  }
#pragma unroll
  for (int off = 32; off > 0; off >>= 1) ss += __shfl_xor(ss, off, 64);
  const float sc = 32.0f / fmaxf(sqrtf(ss), 1e-8f);  // x32 undone by ACC_SCALE
  int* op = (int*)(zn8 + (size_t)row * D);
#pragma unroll
  for (int j = 0; j < 4; ++j) {
    int p = __builtin_amdgcn_cvt_pk_fp8_f32(v[j].x * sc, v[j].y * sc, 0, false);
    p = __builtin_amdgcn_cvt_pk_fp8_f32(v[j].z * sc, v[j].w * sc, p, true);
    op[l + 64 * j] = p;
  }
}

// Phase 2: 256x256 lower-triangle tile per block, 512 threads (8 waves, 4x2).
// fp8 BK=128 slab: A 32KB + B 32KB single-buffered = 64KB -> 2 blocks/CU.
__global__ __launch_bounds__(512, 4) void k_tile(const unsigned char* __restrict__ zn8,
                                                 float* __restrict__ rowsum,
                                                 float* __restrict__ pos) {
  extern __shared__ __align__(16) char smem[];  // 65536
  const int tid = threadIdx.x;
  const int w = tid >> 6, l = tid & 63;

  // decode blockIdx -> lower-triangle (tr, tc), tr >= tc, over 32x32 tile grid
  const int b = blockIdx.x;
  int tr = (int)((sqrtf(8.0f * (float)b + 1.0f) - 1.0f) * 0.5f);
  if (tr * (tr + 1) / 2 > b) --tr;
  if ((tr + 1) * (tr + 2) / 2 <= b) ++tr;
  const int tc = b - tr * (tr + 1) / 2;
  const bool diag = (tr == tc);

  const int wr = w >> 1, wc = w & 1;
  const int m = l & 15, kg = l >> 4;
  const int rowA0 = tr * 256, colB0 = tc * 256;

  f32x4 acc[4][8] = {};

  // staging: per matrix per slab 2048 slots x 16B (256 rows x 8 chunks).
  // phys slot s -> row s>>3; phys chunk s&7 holds logical chunk (s&7)^(row&7).
  int srow[4], scol[4];
#pragma unroll
  for (int j = 0; j < 4; ++j) {
    int s = j * 512 + tid;
    int r = s >> 3;
    srow[j] = r;
    scol[j] = (s & 7) ^ (r & 7);
  }

  // fragment reads: logical chunks kg and kg+4 (K-permuted; A/B identical)
  const int csw0 = (kg ^ (m & 7)) * 16;
  const int csw1 = ((kg + 4) ^ (m & 7)) * 16;

  for (int kt = 0; kt < 8; ++kt) {
    const size_t kb = (size_t)kt * 128;
    {  // stage slab kt (async -> LDS); barrier below drains vmcnt
      char* ab = smem;
#pragma unroll
      for (int j = 0; j < 4; ++j) {
        const int s = j * 512 + tid;
        gload16((const char*)zn8 + ((size_t)(rowA0 + srow[j]) * D + kb + scol[j] * 16), ab + s * 16);
      }
      if (!diag) {
        char* bb = smem + 32768;
#pragma unroll
        for (int j = 0; j < 4; ++j) {
          const int s = j * 512 + tid;
          gload16((const char*)zn8 + ((size_t)(colB0 + srow[j]) * D + kb + scol[j] * 16), bb + s * 16);
        }
      }
    }
    __syncthreads();  // staging complete

    const char* ab = smem;
    const char* bb = diag ? ab : (ab + 32768);
    lx2 a0[4], a1[4];
#pragma unroll
    for (int mt = 0; mt < 4; ++mt) {
      const char* rp = ab + (wr * 64 + mt * 16 + m) * 128;
      a0[mt] = *(const lx2*)(rp + csw0);
      a1[mt] = *(const lx2*)(rp + csw1);
    }
#pragma unroll
    for (int nt = 0; nt < 8; ++nt) {
      const char* rp = bb + (wc * 128 + nt * 16 + m) * 128;
      const lx2 b0 = *(const lx2*)(rp + csw0);
      const lx2 b1 = *(const lx2*)(rp + csw1);
#pragma unroll
      for (int mt = 0; mt < 4; ++mt) {
        acc[mt][nt] = __builtin_amdgcn_mfma_f32_16x16x32_fp8_fp8(a0[mt].x, b0.x, acc[mt][nt], 0, 0, 0);
        acc[mt][nt] = __builtin_amdgcn_mfma_f32_16x16x32_fp8_fp8(a0[mt].y, b0.y, acc[mt][nt], 0, 0, 0);
        acc[mt][nt] = __builtin_amdgcn_mfma_f32_16x16x32_fp8_fp8(a1[mt].x, b1.x, acc[mt][nt], 0, 0, 0);
        acc[mt][nt] = __builtin_amdgcn_mfma_f32_16x16x32_fp8_fp8(a1[mt].y, b1.y, acc[mt][nt], 0, 0, 0);
      }
    }
    __syncthreads();  // all frags consumed before next slab overwrites
  }

  // Epilogue. C/D layout: col=l&15, row=(l>>4)*4+reg.
  const int quad = l >> 4;
  const int col = l & 15;
  float cs[8] = {0.f, 0.f, 0.f, 0.f, 0.f, 0.f, 0.f, 0.f};
#pragma unroll
  for (int mt = 0; mt < 4; ++mt) {
    float rs[4] = {0.f, 0.f, 0.f, 0.f};
#pragma unroll
    for (int nt = 0; nt < 8; ++nt) {
      const int gcol = colB0 + wc * 128 + nt * 16 + col;
#pragma unroll
      for (int r = 0; r < 4; ++r) {
        const int grow = rowA0 + wr * 64 + mt * 16 + quad * 4 + r;
        const float t = acc[mt][nt][r] * ACC_SCALE;
        if (gcol == (grow ^ (N / 2))) {  // pos pair; never in diag tiles
          pos[grow] = t;
          pos[gcol] = t;  // S symmetric
        }
        const float e = (gcol == grow) ? 0.0f : __expf(t - INV_T);
        rs[r] += e;
        cs[nt] += e;
      }
    }
#pragma unroll
    for (int off = 1; off < 16; off <<= 1) {
#pragma unroll
      for (int r = 0; r < 4; ++r) rs[r] += __shfl_xor(rs[r], off, 64);
    }
    if (col == 0) {
#pragma unroll
      for (int r = 0; r < 4; ++r)
        atomicAdd(&rowsum[rowA0 + wr * 64 + mt * 16 + quad * 4 + r], rs[r]);
    }
  }
  if (!diag) {  // col sums = row-sums for block tc rows (symmetry)
#pragma unroll
    for (int nt = 0; nt < 8; ++nt) {
      cs[nt] += __shfl_xor(cs[nt], 16, 64);
      cs[nt] += __shfl_xor(cs[nt], 32, 64);
    }
    if (l < 16) {
#pragma unroll
      for (int nt = 0; nt < 8; ++nt)
        atomicAdd(&rowsum[colB0 + wc * 128 + nt * 16 + l], cs[nt]);
    }
  }
}

// Phase 3: single block: out = mean(-pos + C + log(rowsum)).
__global__ __launch_bounds__(1024) void k_final(const float* __restrict__ rowsum,
                                                const float* __restrict__ pos,
                                                float* __restrict__ out) {
  const int t = threadIdx.x;
  float s = 0.f;
  for (int i = t; i < N; i += 1024) s += INV_T + __logf(rowsum[i]) - pos[i];
#pragma unroll
  for (int off = 32; off > 0; off >>= 1) s += __shfl_down(s, off, 64);
  __shared__ float red[16];
  if ((t & 63) == 0) red[t >> 6] = s;
  __syncthreads();
  if (t == 0) {
    float tot = 0.f;
#pragma unroll
    for (int j = 0; j < 16; ++j) tot += red[j];
    out[0] = tot * (1.0f / N);
  }
}

extern "C" void kernel_launch(void* const* d_in, const int* in_sizes, int n_in,
                              void* d_out, int out_size, void* d_ws, size_t ws_size,
                              hipStream_t stream) {
  const float* z = (const float*)d_in[0];
  float* out = (float*)d_out;
  char* ws = (char*)d_ws;
  unsigned char* zn8 = (unsigned char*)ws;                    // 8 MiB fp8
  float* rowsum = (float*)(ws + (size_t)N * D);               // 32 KiB
  float* pos = (float*)(ws + (size_t)N * D + (size_t)N * 4);  // 32 KiB

  k_normalize<<<N / 4, 256, 0, stream>>>(z, zn8, rowsum);
  k_tile<<<NTILES, 512, 65536, stream>>>(zn8, rowsum, pos);
  k_final<<<1, 1024, 0, stream>>>(rowsum, pos, out);
}

// Round 9
// 181.307 us; speedup vs baseline: 2.5688x; 2.5688x over previous
//
#include <hip/hip_runtime.h>
#include <hip/hip_bf16.h>

// ContrastiveLoss: z (8192x1024 fp32) -> scalar
//   zn = z / max(||z||,eps); S = zn@zn^T; diag=MASK; /T; nll = -S[i,i^4096] + lse(S[i,:]); mean
// R9: co-residency instead of double-buffering. 128x128 lower-tri tiles,
// 256 threads (4 waves 2x2), wave 64x64 = 4x4 frags -> acc 64 VGPR, total
// ~112 <= 128 cap from __launch_bounds__(256,4) => 4 blocks/CU (R8 lesson:
// never cap below acc size). Single-buffered 32KB LDS; co-resident blocks
// hide each other's stage/barrier/read convoy. fp8 e4m3 16x16x32 MFMA,
// K-permuted b128 frag reads (chunks kg,kg+4), 128B rows + chunk^(row&7)
// swizzle (R2/R7-verified 0 conflicts). Fixed-shift logsumexp via atomicAdd.

#define N 8192
#define D 1024
#define INV_T 14.285714285714286f
#define NT128 64
#define NTILES (NT128 * (NT128 + 1) / 2)  // 2080
#define ACC_SCALE (INV_T / 1024.0f)       // undo fp8 x32 scaling on both operands

typedef float f32x4 __attribute__((ext_vector_type(4)));
typedef long lx2 __attribute__((ext_vector_type(2)));

__device__ inline void gload16(const void* g, void* l) {
  __builtin_amdgcn_global_load_lds(
      (const __attribute__((address_space(1))) void*)g,
      (__attribute__((address_space(3))) void*)l, 16, 0, 0);
}

// Phase 1: one wave per row, no barriers. Row-normalize, scale x32, fp8 e4m3.
__global__ __launch_bounds__(256) void k_normalize(const float* __restrict__ z,
                                                   unsigned char* __restrict__ zn8,
                                                   float* __restrict__ rowsum) {
  const int t = threadIdx.x;
  const int l = t & 63, w = t >> 6;
  const int row = blockIdx.x * 4 + w;
  if (blockIdx.x < 32) rowsum[blockIdx.x * 256 + t] = 0.0f;
  const float4* zr = (const float4*)(z + (size_t)row * D);
  float4 v[4];
  float ss = 0.f;
#pragma unroll
  for (int j = 0; j < 4; ++j) {
    v[j] = zr[l + 64 * j];
    ss += v[j].x * v[j].x + v[j].y * v[j].y + v[j].z * v[j].z + v[j].w * v[j].w;
  }
#pragma unroll
  for (int off = 32; off > 0; off >>= 1) ss += __shfl_xor(ss, off, 64);
  const float sc = 32.0f / fmaxf(sqrtf(ss), 1e-8f);  // x32 undone by ACC_SCALE
  int* op = (int*)(zn8 + (size_t)row * D);
#pragma unroll
  for (int j = 0; j < 4; ++j) {
    int p = __builtin_amdgcn_cvt_pk_fp8_f32(v[j].x * sc, v[j].y * sc, 0, false);
    p = __builtin_amdgcn_cvt_pk_fp8_f32(v[j].z * sc, v[j].w * sc, p, true);
    op[l + 64 * j] = p;
  }
}

// Phase 2: 128x128 lower-triangle tile per block, 256 threads (4 waves, 2x2).
// fp8 BK=128 slab: A 16KB + B 16KB single-buffered = 32KB -> 4 blocks/CU.
__global__ __launch_bounds__(256, 4) void k_tile(const unsigned char* __restrict__ zn8,
                                                 float* __restrict__ rowsum,
                                                 float* __restrict__ pos) {
  __shared__ __align__(16) char smem[32768];
  const int tid = threadIdx.x;
  const int w = tid >> 6, l = tid & 63;

  // decode blockIdx -> lower-triangle (tr, tc), tr >= tc, over 64x64 tile grid
  const int b = blockIdx.x;
  int tr = (int)((sqrtf(8.0f * (float)b + 1.0f) - 1.0f) * 0.5f);
  if (tr * (tr + 1) / 2 > b) --tr;
  if ((tr + 1) * (tr + 2) / 2 <= b) ++tr;
  const int tc = b - tr * (tr + 1) / 2;
  const bool diag = (tr == tc);

  const int wr = w >> 1, wc = w & 1;
  const int m = l & 15, kg = l >> 4;
  const int rowA0 = tr * 128, colB0 = tc * 128;

  f32x4 acc[4][4] = {};

  // staging: per matrix per slab 1024 slots x 16B (128 rows x 8 chunks).
  // phys slot s -> row s>>3; phys chunk s&7 holds logical chunk (s&7)^(row&7).
  int srow[4], scol[4];
#pragma unroll
  for (int j = 0; j < 4; ++j) {
    int s = j * 256 + tid;
    int r = s >> 3;
    srow[j] = r;
    scol[j] = (s & 7) ^ (r & 7);
  }

  // fragment reads: logical chunks kg and kg+4 (K-permuted; A/B identical)
  const int csw0 = (kg ^ (m & 7)) * 16;
  const int csw1 = ((kg + 4) ^ (m & 7)) * 16;

  for (int kt = 0; kt < 8; ++kt) {
    const size_t kb = (size_t)kt * 128;
    {  // stage slab kt (async -> LDS); barrier below drains vmcnt
      char* ab = smem;
#pragma unroll
      for (int j = 0; j < 4; ++j) {
        const int s = j * 256 + tid;
        gload16((const char*)zn8 + ((size_t)(rowA0 + srow[j]) * D + kb + scol[j] * 16), ab + s * 16);
      }
      if (!diag) {
        char* bb = smem + 16384;
#pragma unroll
        for (int j = 0; j < 4; ++j) {
          const int s = j * 256 + tid;
          gload16((const char*)zn8 + ((size_t)(colB0 + srow[j]) * D + kb + scol[j] * 16), bb + s * 16);
        }
      }
    }
    __syncthreads();  // staging complete

    const char* ab = smem;
    const char* bb = diag ? ab : (ab + 16384);
    lx2 a0[4], a1[4];
#pragma unroll
    for (int mt = 0; mt < 4; ++mt) {
      const char* rp = ab + (wr * 64 + mt * 16 + m) * 128;
      a0[mt] = *(const lx2*)(rp + csw0);
      a1[mt] = *(const lx2*)(rp + csw1);
    }
#pragma unroll
    for (int nt = 0; nt < 4; ++nt) {
      const char* rp = bb + (wc * 64 + nt * 16 + m) * 128;
      const lx2 b0 = *(const lx2*)(rp + csw0);
      const lx2 b1 = *(const lx2*)(rp + csw1);
#pragma unroll
      for (int mt = 0; mt < 4; ++mt) {
        acc[mt][nt] = __builtin_amdgcn_mfma_f32_16x16x32_fp8_fp8(a0[mt].x, b0.x, acc[mt][nt], 0, 0, 0);
        acc[mt][nt] = __builtin_amdgcn_mfma_f32_16x16x32_fp8_fp8(a0[mt].y, b0.y, acc[mt][nt], 0, 0, 0);
        acc[mt][nt] = __builtin_amdgcn_mfma_f32_16x16x32_fp8_fp8(a1[mt].x, b1.x, acc[mt][nt], 0, 0, 0);
        acc[mt][nt] = __builtin_amdgcn_mfma_f32_16x16x32_fp8_fp8(a1[mt].y, b1.y, acc[mt][nt], 0, 0, 0);
      }
    }
    __syncthreads();  // all frags consumed before next slab overwrites
  }

  // Epilogue. C/D layout: col=l&15, row=(l>>4)*4+reg.
  const int quad = l >> 4;
  const int col = l & 15;
  float cs[4] = {0.f, 0.f, 0.f, 0.f};
#pragma unroll
  for (int mt = 0; mt < 4; ++mt) {
    float rs[4] = {0.f, 0.f, 0.f, 0.f};
#pragma unroll
    for (int nt = 0; nt < 4; ++nt) {
      const int gcol = colB0 + wc * 64 + nt * 16 + col;
#pragma unroll
      for (int r = 0; r < 4; ++r) {
        const int grow = rowA0 + wr * 64 + mt * 16 + quad * 4 + r;
        const float t = acc[mt][nt][r] * ACC_SCALE;
        if (gcol == (grow ^ (N / 2))) {  // pos pair; never in diag tiles
          pos[grow] = t;
          pos[gcol] = t;  // S symmetric
        }
        const float e = (gcol == grow) ? 0.0f : __expf(t - INV_T);
        rs[r] += e;
        cs[nt] += e;
      }
    }
#pragma unroll
    for (int off = 1; off < 16; off <<= 1) {
#pragma unroll
      for (int r = 0; r < 4; ++r) rs[r] += __shfl_xor(rs[r], off, 64);
    }
    if (col == 0) {
#pragma unroll
      for (int r = 0; r < 4; ++r)
        atomicAdd(&rowsum[rowA0 + wr * 64 + mt * 16 + quad * 4 + r], rs[r]);
    }
  }
  if (!diag) {  // col sums = row-sums for block tc rows (symmetry)
#pragma unroll
    for (int nt = 0; nt < 4; ++nt) {
      cs[nt] += __shfl_xor(cs[nt], 16, 64);
      cs[nt] += __shfl_xor(cs[nt], 32, 64);
    }
    if (l < 16) {
#pragma unroll
      for (int nt = 0; nt < 4; ++nt)
        atomicAdd(&rowsum[colB0 + wc * 64 + nt * 16 + l], cs[nt]);
    }
  }
}

// Phase 3: single block: out = mean(-pos + C + log(rowsum)).
__global__ __launch_bounds__(1024) void k_final(const float* __restrict__ rowsum,
                                                const float* __restrict__ pos,
                                                float* __restrict__ out) {
  const int t = threadIdx.x;
  float s = 0.f;
  for (int i = t; i < N; i += 1024) s += INV_T + __logf(rowsum[i]) - pos[i];
#pragma unroll
  for (int off = 32; off > 0; off >>= 1) s += __shfl_down(s, off, 64);
  __shared__ float red[16];
  if ((t & 63) == 0) red[t >> 6] = s;
  __syncthreads();
  if (t == 0) {
    float tot = 0.f;
#pragma unroll
    for (int j = 0; j < 16; ++j) tot += red[j];
    out[0] = tot * (1.0f / N);
  }
}

extern "C" void kernel_launch(void* const* d_in, const int* in_sizes, int n_in,
                              void* d_out, int out_size, void* d_ws, size_t ws_size,
                              hipStream_t stream) {
  const float* z = (const float*)d_in[0];
  float* out = (float*)d_out;
  char* ws = (char*)d_ws;
  unsigned char* zn8 = (unsigned char*)ws;                    // 8 MiB fp8
  float* rowsum = (float*)(ws + (size_t)N * D);               // 32 KiB
  float* pos = (float*)(ws + (size_t)N * D + (size_t)N * 4);  // 32 KiB

  k_normalize<<<N / 4, 256, 0, stream>>>(z, zn8, rowsum);
  k_tile<<<NTILES, 256, 0, stream>>>(zn8, rowsum, pos);
  k_final<<<1, 1024, 0, stream>>>(rowsum, pos, out);
}